// Round 11
// baseline (165.442 us; speedup 1.0000x reference)
//
#include <hip/hip_runtime.h>

typedef _Float16 f16;
typedef f16 f16x4 __attribute__((ext_vector_type(4)));
typedef f16 f16x8 __attribute__((ext_vector_type(8)));
typedef float f32x4 __attribute__((ext_vector_type(4)));

// state_embed (256,512) f32 | action_feats (256,1000,64) f32 | W1 (576,256) | b1 (256)
// W2 (256,128) | b2 (128) | W3 (128,1) | b3 (1)  -> out (256,1000) f32

#define AF_STRIDE 64    // unpadded; XOR swizzle supplies the bank rotation
#define H1_STRIDE 256   // unpadded; XOR swizzle supplies the bank rotation

// ---------- prep: pack W1a^T (A-frag), W2 (B-frag), compute h_state ----------
// R18: REVERTED to the 280-block R8 version. R10's 64-block x 4-row variant cut W1
//   traffic 4x but left ~1 wave/CU (no TLP) -> serial 2048-FMA chain exposed, +9us.
//   Occupancy arithmetic must accompany traffic arithmetic.
__global__ __launch_bounds__(256) void prep_kernel(const float* __restrict__ W1,
                                                   const float* __restrict__ W2,
                                                   const float* __restrict__ state,
                                                   const float* __restrict__ b1,
                                                   f16* __restrict__ pw1at,
                                                   f16* __restrict__ pw2,
                                                   float* __restrict__ hstate) {
    __shared__ float srow[512];
    int blk = blockIdx.x;
    int tid = threadIdx.x;
    if (blk < 24) {
        int idx = blk * 256 + tid;              // 0..6143
        int F = idx >> 6;                       // fragment id 0..95
        int L = idx & 63;
        int q = L >> 4, c = L & 15;
        f16x8 v;
        if (F < 32) {                           // pw1at: M=256h (mt 0..15), K=64f (kt 0..1)
            int mt = F >> 1, kt = F & 1;
            #pragma unroll
            for (int j = 0; j < 8; ++j) {
                int f = kt * 32 + q * 8 + j;
                v[j] = (f16)W1[(size_t)(512 + f) * 256 + mt * 16 + c];
            }
            *(f16x8*)(pw1at + ((size_t)F * 64 + L) * 8) = v;
        } else {                                // pw2: K=256 (kt 0..7), N=128 (nt 0..7)
            int F2 = F - 32;
            int nt = F2 >> 3, kt = F2 & 7;
            #pragma unroll
            for (int j = 0; j < 8; ++j) {
                int k = kt * 32 + q * 8 + j;
                v[j] = (f16)W2[(size_t)k * 128 + nt * 16 + c];
            }
            *(f16x8*)(pw2 + ((size_t)F2 * 64 + L) * 8) = v;
        }
    } else {
        int b = blk - 24;                       // one batch row per block (fp32 exact)
        srow[tid] = state[(size_t)b * 512 + tid];
        srow[tid + 256] = state[(size_t)b * 512 + 256 + tid];
        __syncthreads();
        float a0 = 0.f, a1 = 0.f;
        #pragma unroll 16
        for (int f = 0; f < 512; f += 2) {
            a0 = fmaf(srow[f],     W1[(size_t)f * 256 + tid],       a0);
            a1 = fmaf(srow[f + 1], W1[(size_t)(f + 1) * 256 + tid], a1);
        }
        hstate[(size_t)b * 256 + tid] = a0 + a1 + b1[tid];
    }
}

// ---------- fused MLP: 1 tile x 64 actions/block, h-split waves ----------
// R18 = MEASUREMENT ROUND (pre-committed in R9): fused body reverted to exact R8
//   (best total 132.8us) and DISPATCHED TWICE — pure function, idempotent — so both
//   dispatches surface in the top-5 rocprof table (they hide under the ~41us harness
//   poison fills otherwise). Read dispatch-1 as truth; dispatch-2 delta = L3-warmth
//   sensitivity (the 268MB poison fill evicts afeat from L3 between iterations).
//   Deliberate +~36us total this round; reverts to single dispatch in R19.
__global__ __launch_bounds__(256, 3) void fused_kernel(const float* __restrict__ afeat,
                                                       const float* __restrict__ hstate,
                                                       const f16* __restrict__ pw1at,
                                                       const f16* __restrict__ pw2,
                                                       const float* __restrict__ b2,
                                                       const float* __restrict__ W3,
                                                       const float* __restrict__ b3,
                                                       float* __restrict__ out) {
    __shared__ __align__(16) char smem[64 * H1_STRIDE * 2];   // 32768 B
    f16* h1s = (f16*)smem;                                 // 64 rows x 256 f16, swizzled
    f16* afs = (f16*)(smem + 24576);                       // aliases h1s rows 48..63
    float* lds3 = (float*)smem;                            // aliases h1s rows 0..2

    int tid = threadIdx.x;
    int w = tid >> 6;                 // wave 0..3
    int L = tid & 63;
    int q = L >> 4, c = L & 15;
    int r0 = blockIdx.x * 64;         // first global action row of this block's tile

    // ---- issue HBM stage loads FIRST (longest latency) ----
    f32x4 sl[2][2];
    #pragma unroll
    for (int i = 0; i < 2; ++i) {
        int id = i * 256 + tid;               // 32B-chunk id 0..511
        int row = id >> 3, c32 = id & 7;
        const float* p = afeat + (size_t)(r0 + row) * 64 + c32 * 8;
        sl[i][0] = *(const f32x4*)p;
        sl[i][1] = *(const f32x4*)(p + 4);
    }

    // ---- L2 loads: resident W1a^T A-frags (32 VGPRs), wave's h-slice [64w,64w+64) ----
    f16x8 a1f[4][2];
    #pragma unroll
    for (int i = 0; i < 4; ++i)
        #pragma unroll
        for (int kt = 0; kt < 2; ++kt)
            a1f[i][kt] = *(const f16x8*)(pw1at + ((size_t)((4 * w + i) * 2 + kt) * 64 + L) * 8);

    int b0i = r0 / 1000;
    int boundary = (b0i + 1) * 1000;
    int b1i = b0i < 255 ? b0i + 1 : 255;

    // ---- hoisted hstate: both candidate batch rows, wave's h-slice ----
    f32x4 hsva[4], hsvb[4];
    #pragma unroll
    for (int i = 0; i < 4; ++i) {
        int hbase = (4 * w + i) * 16 + q * 4;
        hsva[i] = *(const f32x4*)(hstate + (size_t)b0i * 256 + hbase);
        hsvb[i] = *(const f32x4*)(hstate + (size_t)b1i * 256 + hbase);
    }

    // ---- convert + write afs (consumes sl) ----
    #pragma unroll
    for (int i = 0; i < 2; ++i) {
        int id = i * 256 + tid;
        int row = id >> 3, c32 = id & 7;
        f16x8 v;
        v[0] = (f16)sl[i][0][0]; v[1] = (f16)sl[i][0][1];
        v[2] = (f16)sl[i][0][2]; v[3] = (f16)sl[i][0][3];
        v[4] = (f16)sl[i][1][0]; v[5] = (f16)sl[i][1][1];
        v[6] = (f16)sl[i][1][2]; v[7] = (f16)sl[i][1][3];
        *(f16x8*)(afs + row * AF_STRIDE + ((c32 * 8) ^ ((row & 7) << 3))) = v;
    }
    __syncthreads();   // B0: afs staged

    int sx = (c & 7) << 3;            // lane's row-class XOR in f16 units (rows are X*16+c)
    unsigned bo = ((q * 8) ^ sx) * 2; // byte offset inside 64-f16 swizzle class, kt-even

    // ---- GEMM1 B-frags via base+imm: byte = c*128 + nt*2048 + (bo ^ (kt*64)) ----
    const char* Bp0 = (const char*)afs + c * 128 + bo;
    const char* Bp1 = (const char*)afs + c * 128 + (bo ^ 64);
    f16x8 bf[4][2];
    #pragma unroll
    for (int nt = 0; nt < 4; ++nt) {
        bf[nt][0] = *(const f16x8*)(Bp0 + nt * 2048);
        bf[nt][1] = *(const f16x8*)(Bp1 + nt * 2048);
    }
    __syncthreads();   // B0.5: all waves' afs reads done -> h1s tail (aliasing afs) writable

    // ---- GEMM1, hstate folded into C-init; relu in packed f16 ----
    const f16x4 zf = {(f16)0.f, (f16)0.f, (f16)0.f, (f16)0.f};
    #pragma unroll
    for (int i = 0; i < 4; ++i) {
        f32x4 acc[4];
        #pragma unroll
        for (int nt = 0; nt < 4; ++nt) {
            bool sel = (r0 + nt * 16 + c) >= boundary;
            acc[nt] = sel ? hsvb[i] : hsva[i];
            #pragma unroll
            for (int kt = 0; kt < 2; ++kt)
                acc[nt] = __builtin_amdgcn_mfma_f32_16x16x32_f16(
                    a1f[i][kt], bf[nt][kt], acc[nt], 0, 0, 0);
        }
        // h1 write: byte = c*512 + nt*8192 + 2*((((4w+i)*16+q*4) ^ sx))
        char* wp = (char*)h1s + c * 512 + ((((4 * w + i) * 16 + q * 4) ^ sx) * 2);
        #pragma unroll
        for (int nt = 0; nt < 4; ++nt) {
            f16x4 hv;
            hv[0] = (f16)acc[nt][0]; hv[1] = (f16)acc[nt][1];
            hv[2] = (f16)acc[nt][2]; hv[3] = (f16)acc[nt][3];
            hv = __builtin_elementwise_max(hv, zf);
            *(f16x4*)(wp + nt * 8192) = hv;
        }
    }
    __syncthreads();   // B1: h1s ready

    // ---- GEMM2 (swapped): D[m=g][n=action], wave owns gt=2w,2w+1; depth-2 on both ops ----
    f32x4 b2v[2], w3v[2];
    #pragma unroll
    for (int gti = 0; gti < 2; ++gti) {
        int gb = (2 * w + gti) * 16 + q * 4;
        b2v[gti] = *(const f32x4*)(b2 + gb);
        w3v[gti] = *(const f32x4*)(W3 + gb);
    }
    float b3v = b3[0];

    // a2 read: byte = c*512 + rb*8192 + (kt>>1)*128 + (bo ^ ((kt&1)*64))
    const char* Ap0 = (const char*)h1s + c * 512 + bo;
    const char* Ap1 = (const char*)h1s + c * 512 + (bo ^ 64);

    f32x4 acc2[4][2];
    #pragma unroll
    for (int rb = 0; rb < 4; ++rb) {
        acc2[rb][0] = (f32x4){0.f, 0.f, 0.f, 0.f};
        acc2[rb][1] = (f32x4){0.f, 0.f, 0.f, 0.f};
    }

    f16x8 a2[2][4], pwf[2][2];
    #pragma unroll
    for (int rb = 0; rb < 4; ++rb)
        a2[0][rb] = *(const f16x8*)(Ap0 + rb * 8192);
    #pragma unroll
    for (int gti = 0; gti < 2; ++gti)
        pwf[0][gti] = *(const f16x8*)(pw2 + ((size_t)((2 * w + gti) * 8) * 64 + L) * 8);

    #pragma unroll
    for (int kt = 0; kt < 8; ++kt) {
        if (kt < 7) {
            const char* Apn = ((kt + 1) & 1) ? Ap1 : Ap0;
            #pragma unroll
            for (int rb = 0; rb < 4; ++rb)
                a2[(kt + 1) & 1][rb] =
                    *(const f16x8*)(Apn + ((kt + 1) >> 1) * 128 + rb * 8192);
            #pragma unroll
            for (int gti = 0; gti < 2; ++gti)
                pwf[(kt + 1) & 1][gti] =
                    *(const f16x8*)(pw2 + ((size_t)((2 * w + gti) * 8 + kt + 1) * 64 + L) * 8);
        }
        __builtin_amdgcn_s_setprio(1);
        #pragma unroll
        for (int gti = 0; gti < 2; ++gti)
            #pragma unroll
            for (int rb = 0; rb < 4; ++rb)
                acc2[rb][gti] = __builtin_amdgcn_mfma_f32_16x16x32_f16(
                    pwf[kt & 1][gti], a2[kt & 1][rb], acc2[rb][gti], 0, 0, 0);
        __builtin_amdgcn_s_setprio(0);
    }

    // ---- layer 3: in-lane relu+dot over this wave's 32 g; reduce over q then waves ----
    float pa[4];
    #pragma unroll
    for (int rb = 0; rb < 4; ++rb) {
        float s = 0.f;
        #pragma unroll
        for (int gti = 0; gti < 2; ++gti)
            #pragma unroll
            for (int reg = 0; reg < 4; ++reg) {
                float v = acc2[rb][gti][reg] + b2v[gti][reg];
                v = v > 0.f ? v : 0.f;
                s = fmaf(v, w3v[gti][reg], s);
            }
        pa[rb] = s;
    }
    #pragma unroll
    for (int rb = 0; rb < 4; ++rb) {
        pa[rb] += __shfl_xor(pa[rb], 16);
        pa[rb] += __shfl_xor(pa[rb], 32);
    }
    __syncthreads();   // B1.5: all waves' h1s reads done -> lds3 (aliasing h1s) writable
    if (L < 16) {
        #pragma unroll
        for (int rb = 0; rb < 4; ++rb)
            lds3[(rb * 16 + L) * 6 + w] = pa[rb];
    }
    __syncthreads();   // B2: lds3 ready

    if (tid < 64) {
        const float* pm = lds3 + tid * 6;
        out[r0 + tid] = pm[0] + pm[1] + pm[2] + pm[3] + b3v;
    }
}

extern "C" void kernel_launch(void* const* d_in, const int* in_sizes, int n_in,
                              void* d_out, int out_size, void* d_ws, size_t ws_size,
                              hipStream_t stream) {
    const float* state = (const float*)d_in[0];
    const float* afeat = (const float*)d_in[1];
    const float* W1    = (const float*)d_in[2];
    const float* b1    = (const float*)d_in[3];
    const float* W2    = (const float*)d_in[4];
    const float* b2    = (const float*)d_in[5];
    const float* W3    = (const float*)d_in[6];
    const float* b3    = (const float*)d_in[7];
    float* out = (float*)d_out;

    // ws: hstate 256KB | pw1at 32KB (16384 f16) | pw2 64KB (32768 f16)
    float* hstate = (float*)d_ws;
    f16* pw1at = (f16*)((char*)d_ws + 65536 * sizeof(float));
    f16* pw2   = pw1at + 16384;

    prep_kernel<<<280, 256, 0, stream>>>(W1, W2, state, b1, pw1at, pw2, hstate);
    // MEASUREMENT ROUND: fused dispatched twice (idempotent pure function) so its
    // counters surface above the ~41us harness poison fills. Revert to single in R19.
    fused_kernel<<<4000, 256, 0, stream>>>(afeat, hstate, pw1at, pw2, b2, W3, b3, out);
    fused_kernel<<<4000, 256, 0, stream>>>(afeat, hstate, pw1at, pw2, b2, W3, b3, out);
}

// Round 13
// 131.507 us; speedup vs baseline: 1.2580x; 1.2580x over previous
//
#include <hip/hip_runtime.h>

typedef _Float16 f16;
typedef f16 f16x4 __attribute__((ext_vector_type(4)));
typedef f16 f16x8 __attribute__((ext_vector_type(8)));
typedef float f32x4 __attribute__((ext_vector_type(4)));

// state_embed (256,512) f32 | action_feats (256,1000,64) f32 | W1 (576,256) | b1 (256)
// W2 (256,128) | b2 (128) | W3 (128,1) | b3 (1)  -> out (256,1000) f32

#define AF_STRIDE 64    // unpadded; XOR swizzle supplies the bank rotation
#define H1_STRIDE 256   // unpadded; XOR swizzle supplies the bank rotation

// ---------- prep: pack W1a^T (A-frag), W2 (B-frag), compute h_state ----------
// 280-block version (R8, known-good ~4.3us). R10's low-block variant regressed:
//   traffic arithmetic without occupancy arithmetic.
__global__ __launch_bounds__(256) void prep_kernel(const float* __restrict__ W1,
                                                   const float* __restrict__ W2,
                                                   const float* __restrict__ state,
                                                   const float* __restrict__ b1,
                                                   f16* __restrict__ pw1at,
                                                   f16* __restrict__ pw2,
                                                   float* __restrict__ hstate) {
    __shared__ float srow[512];
    int blk = blockIdx.x;
    int tid = threadIdx.x;
    if (blk < 24) {
        int idx = blk * 256 + tid;              // 0..6143
        int F = idx >> 6;                       // fragment id 0..95
        int L = idx & 63;
        int q = L >> 4, c = L & 15;
        f16x8 v;
        if (F < 32) {                           // pw1at: M=256h (mt 0..15), K=64f (kt 0..1)
            int mt = F >> 1, kt = F & 1;
            #pragma unroll
            for (int j = 0; j < 8; ++j) {
                int f = kt * 32 + q * 8 + j;
                v[j] = (f16)W1[(size_t)(512 + f) * 256 + mt * 16 + c];
            }
            *(f16x8*)(pw1at + ((size_t)F * 64 + L) * 8) = v;
        } else {                                // pw2: K=256 (kt 0..7), N=128 (nt 0..7)
            int F2 = F - 32;
            int nt = F2 >> 3, kt = F2 & 7;
            #pragma unroll
            for (int j = 0; j < 8; ++j) {
                int k = kt * 32 + q * 8 + j;
                v[j] = (f16)W2[(size_t)k * 128 + nt * 16 + c];
            }
            *(f16x8*)(pw2 + ((size_t)F2 * 64 + L) * 8) = v;
        }
    } else {
        int b = blk - 24;                       // one batch row per block (fp32 exact)
        srow[tid] = state[(size_t)b * 512 + tid];
        srow[tid + 256] = state[(size_t)b * 512 + 256 + tid];
        __syncthreads();
        float a0 = 0.f, a1 = 0.f;
        #pragma unroll 16
        for (int f = 0; f < 512; f += 2) {
            a0 = fmaf(srow[f],     W1[(size_t)f * 256 + tid],       a0);
            a1 = fmaf(srow[f + 1], W1[(size_t)(f + 1) * 256 + tid], a1);
        }
        hstate[(size_t)b * 256 + tid] = a0 + a1 + b1[tid];
    }
}

// ---------- fused MLP: 1 tile x 64 actions/block, h-split waves ----------
// MEASURED (R18): fused marginal = 32.6us warm; pipe floors ~14us -> ~18us latency gap.
// THEORY (single variable; R12 bench was container-infra failure, kernel unchanged):
//   GEMM2 pw2 L2-latency exposure. Per kt: 16 MFMA ~= 78cy of cover vs ~200-300cy
//   L2 hit -> ~150-250cy stall x 8kt per wave. Depth-4 pwf ring (prefetch kt+3
//   ~= 234cy ahead) removes it — needs ~120 live regs in GEMM2, impossible under
//   (256,3)'s cap 80 [LAUNCH-BOUNDS LAW R2/R6/R7: cap ~= floor(256/min_waves)].
//   Hence (256,2) cap 128. pwf preload issued AFTER GEMM1's regs die -> live ~50
//   at hoist point, GEMM2 steady ~120 <= 128. LDS 32768 -> 4 blk/CU (VGPR-limited).
// Pre-commit: total >= 131.5 falsifies; next round = inner-repeat counter capture.
__global__ __launch_bounds__(256, 2) void fused_kernel(const float* __restrict__ afeat,
                                                       const float* __restrict__ hstate,
                                                       const f16* __restrict__ pw1at,
                                                       const f16* __restrict__ pw2,
                                                       const float* __restrict__ b2,
                                                       const float* __restrict__ W3,
                                                       const float* __restrict__ b3,
                                                       float* __restrict__ out) {
    __shared__ __align__(16) char smem[64 * H1_STRIDE * 2];   // 32768 B
    f16* h1s = (f16*)smem;                                 // 64 rows x 256 f16, swizzled
    f16* afs = (f16*)(smem + 24576);                       // aliases h1s rows 48..63
    float* lds3 = (float*)smem;                            // aliases h1s rows 0..2

    int tid = threadIdx.x;
    int w = tid >> 6;                 // wave 0..3
    int L = tid & 63;
    int q = L >> 4, c = L & 15;
    int r0 = blockIdx.x * 64;         // first global action row of this block's tile

    // ---- issue HBM stage loads FIRST (longest latency) ----
    f32x4 sl[2][2];
    #pragma unroll
    for (int i = 0; i < 2; ++i) {
        int id = i * 256 + tid;               // 32B-chunk id 0..511
        int row = id >> 3, c32 = id & 7;
        const float* p = afeat + (size_t)(r0 + row) * 64 + c32 * 8;
        sl[i][0] = *(const f32x4*)p;
        sl[i][1] = *(const f32x4*)(p + 4);
    }

    // ---- L2 loads: resident W1a^T A-frags (32 VGPRs), wave's h-slice [64w,64w+64) ----
    f16x8 a1f[4][2];
    #pragma unroll
    for (int i = 0; i < 4; ++i)
        #pragma unroll
        for (int kt = 0; kt < 2; ++kt)
            a1f[i][kt] = *(const f16x8*)(pw1at + ((size_t)((4 * w + i) * 2 + kt) * 64 + L) * 8);

    int b0i = r0 / 1000;
    int boundary = (b0i + 1) * 1000;
    int b1i = b0i < 255 ? b0i + 1 : 255;

    // ---- hoisted hstate: both candidate batch rows, wave's h-slice ----
    f32x4 hsva[4], hsvb[4];
    #pragma unroll
    for (int i = 0; i < 4; ++i) {
        int hbase = (4 * w + i) * 16 + q * 4;
        hsva[i] = *(const f32x4*)(hstate + (size_t)b0i * 256 + hbase);
        hsvb[i] = *(const f32x4*)(hstate + (size_t)b1i * 256 + hbase);
    }

    // ---- convert + write afs (consumes sl) ----
    #pragma unroll
    for (int i = 0; i < 2; ++i) {
        int id = i * 256 + tid;
        int row = id >> 3, c32 = id & 7;
        f16x8 v;
        v[0] = (f16)sl[i][0][0]; v[1] = (f16)sl[i][0][1];
        v[2] = (f16)sl[i][0][2]; v[3] = (f16)sl[i][0][3];
        v[4] = (f16)sl[i][1][0]; v[5] = (f16)sl[i][1][1];
        v[6] = (f16)sl[i][1][2]; v[7] = (f16)sl[i][1][3];
        *(f16x8*)(afs + row * AF_STRIDE + ((c32 * 8) ^ ((row & 7) << 3))) = v;
    }
    __syncthreads();   // B0: afs staged

    int sx = (c & 7) << 3;            // lane's row-class XOR in f16 units (rows are X*16+c)
    unsigned bo = ((q * 8) ^ sx) * 2; // byte offset inside 64-f16 swizzle class, kt-even

    // ---- GEMM1 B-frags via base+imm: byte = c*128 + nt*2048 + (bo ^ (kt*64)) ----
    const char* Bp0 = (const char*)afs + c * 128 + bo;
    const char* Bp1 = (const char*)afs + c * 128 + (bo ^ 64);
    f16x8 bf[4][2];
    #pragma unroll
    for (int nt = 0; nt < 4; ++nt) {
        bf[nt][0] = *(const f16x8*)(Bp0 + nt * 2048);
        bf[nt][1] = *(const f16x8*)(Bp1 + nt * 2048);
    }
    __syncthreads();   // B0.5: all waves' afs reads done -> h1s tail (aliasing afs) writable

    // ---- GEMM1, hstate folded into C-init; relu in packed f16 ----
    const f16x4 zf = {(f16)0.f, (f16)0.f, (f16)0.f, (f16)0.f};
    #pragma unroll
    for (int i = 0; i < 4; ++i) {
        f32x4 acc[4];
        #pragma unroll
        for (int nt = 0; nt < 4; ++nt) {
            bool sel = (r0 + nt * 16 + c) >= boundary;
            acc[nt] = sel ? hsvb[i] : hsva[i];
            #pragma unroll
            for (int kt = 0; kt < 2; ++kt)
                acc[nt] = __builtin_amdgcn_mfma_f32_16x16x32_f16(
                    a1f[i][kt], bf[nt][kt], acc[nt], 0, 0, 0);
        }
        // h1 write: byte = c*512 + nt*8192 + 2*((((4w+i)*16+q*4) ^ sx))
        char* wp = (char*)h1s + c * 512 + ((((4 * w + i) * 16 + q * 4) ^ sx) * 2);
        #pragma unroll
        for (int nt = 0; nt < 4; ++nt) {
            f16x4 hv;
            hv[0] = (f16)acc[nt][0]; hv[1] = (f16)acc[nt][1];
            hv[2] = (f16)acc[nt][2]; hv[3] = (f16)acc[nt][3];
            hv = __builtin_elementwise_max(hv, zf);
            *(f16x4*)(wp + nt * 8192) = hv;
        }
    }

    // ---- pwf preload kt=0..2 HERE: GEMM1 regs (a1f/hsv/bf/acc) are dead, live ~50;
    //      L2 latency hides under B1 + other waves' GEMM1 tails ----
    f16x8 pwf[4][2];
    #pragma unroll
    for (int kk = 0; kk < 3; ++kk)
        #pragma unroll
        for (int gti = 0; gti < 2; ++gti)
            pwf[kk][gti] = *(const f16x8*)(pw2 + ((size_t)((2 * w + gti) * 8 + kk) * 64 + L) * 8);
    __syncthreads();   // B1: h1s ready

    // ---- GEMM2 (swapped): D[m=g][n=action]; pwf ring depth-4 (kt+3 ahead ~= 234cy),
    //      a2 depth-2 ----
    f32x4 b2v[2], w3v[2];
    #pragma unroll
    for (int gti = 0; gti < 2; ++gti) {
        int gb = (2 * w + gti) * 16 + q * 4;
        b2v[gti] = *(const f32x4*)(b2 + gb);
        w3v[gti] = *(const f32x4*)(W3 + gb);
    }
    float b3v = b3[0];

    // a2 read: byte = c*512 + rb*8192 + (kt>>1)*128 + (bo ^ ((kt&1)*64))
    const char* Ap0 = (const char*)h1s + c * 512 + bo;
    const char* Ap1 = (const char*)h1s + c * 512 + (bo ^ 64);

    f32x4 acc2[4][2];
    #pragma unroll
    for (int rb = 0; rb < 4; ++rb) {
        acc2[rb][0] = (f32x4){0.f, 0.f, 0.f, 0.f};
        acc2[rb][1] = (f32x4){0.f, 0.f, 0.f, 0.f};
    }

    f16x8 a2[2][4];
    #pragma unroll
    for (int rb = 0; rb < 4; ++rb)
        a2[0][rb] = *(const f16x8*)(Ap0 + rb * 8192);

    #pragma unroll
    for (int kt = 0; kt < 8; ++kt) {
        if (kt < 5) {   // prefetch pwf for kt+3 (static ring index, rule #20 safe)
            #pragma unroll
            for (int gti = 0; gti < 2; ++gti)
                pwf[(kt + 3) & 3][gti] =
                    *(const f16x8*)(pw2 + ((size_t)((2 * w + gti) * 8 + kt + 3) * 64 + L) * 8);
        }
        if (kt < 7) {
            const char* Apn = ((kt + 1) & 1) ? Ap1 : Ap0;
            #pragma unroll
            for (int rb = 0; rb < 4; ++rb)
                a2[(kt + 1) & 1][rb] =
                    *(const f16x8*)(Apn + ((kt + 1) >> 1) * 128 + rb * 8192);
        }
        __builtin_amdgcn_s_setprio(1);
        #pragma unroll
        for (int gti = 0; gti < 2; ++gti)
            #pragma unroll
            for (int rb = 0; rb < 4; ++rb)
                acc2[rb][gti] = __builtin_amdgcn_mfma_f32_16x16x32_f16(
                    pwf[kt & 3][gti], a2[kt & 1][rb], acc2[rb][gti], 0, 0, 0);
        __builtin_amdgcn_s_setprio(0);
    }

    // ---- layer 3: in-lane relu+dot over this wave's 32 g; reduce over q then waves ----
    float pa[4];
    #pragma unroll
    for (int rb = 0; rb < 4; ++rb) {
        float s = 0.f;
        #pragma unroll
        for (int gti = 0; gti < 2; ++gti)
            #pragma unroll
            for (int reg = 0; reg < 4; ++reg) {
                float v = acc2[rb][gti][reg] + b2v[gti][reg];
                v = v > 0.f ? v : 0.f;
                s = fmaf(v, w3v[gti][reg], s);
            }
        pa[rb] = s;
    }
    #pragma unroll
    for (int rb = 0; rb < 4; ++rb) {
        pa[rb] += __shfl_xor(pa[rb], 16);
        pa[rb] += __shfl_xor(pa[rb], 32);
    }
    __syncthreads();   // B1.5: all waves' h1s reads done -> lds3 (aliasing h1s) writable
    if (L < 16) {
        #pragma unroll
        for (int rb = 0; rb < 4; ++rb)
            lds3[(rb * 16 + L) * 6 + w] = pa[rb];
    }
    __syncthreads();   // B2: lds3 ready

    if (tid < 64) {
        const float* pm = lds3 + tid * 6;
        out[r0 + tid] = pm[0] + pm[1] + pm[2] + pm[3] + b3v;
    }
}

extern "C" void kernel_launch(void* const* d_in, const int* in_sizes, int n_in,
                              void* d_out, int out_size, void* d_ws, size_t ws_size,
                              hipStream_t stream) {
    const float* state = (const float*)d_in[0];
    const float* afeat = (const float*)d_in[1];
    const float* W1    = (const float*)d_in[2];
    const float* b1    = (const float*)d_in[3];
    const float* W2    = (const float*)d_in[4];
    const float* b2    = (const float*)d_in[5];
    const float* W3    = (const float*)d_in[6];
    const float* b3    = (const float*)d_in[7];
    float* out = (float*)d_out;

    // ws: hstate 256KB | pw1at 32KB (16384 f16) | pw2 64KB (32768 f16)
    float* hstate = (float*)d_ws;
    f16* pw1at = (f16*)((char*)d_ws + 65536 * sizeof(float));
    f16* pw2   = pw1at + 16384;

    prep_kernel<<<280, 256, 0, stream>>>(W1, W2, state, b1, pw1at, pw2, hstate);
    fused_kernel<<<4000, 256, 0, stream>>>(afeat, hstate, pw1at, pw2, b2, W3, b3, out);
}